// Round 7
// baseline (164.755 us; speedup 1.0000x reference)
//
#include <hip/hip_runtime.h>

#define LSEQ 8194

typedef _Float16 f16x8 __attribute__((ext_vector_type(8)));
typedef _Float16 f16x2 __attribute__((ext_vector_type(2)));
typedef __attribute__((ext_vector_type(4))) float f32x4;

static __device__ __forceinline__ float tanh_fast(float x){
    float p = __expf(2.0f * x);
    float r = __builtin_amdgcn_rcpf(1.0f + p);
    return 1.0f - 2.0f * r;
}
// sum 3 packed-f16x2 taps + relu (v_pk_add_f16 + v_pk_max_f16)
static __device__ __forceinline__ unsigned h3relu(unsigned a, unsigned b, unsigned c){
    union { f16x2 h; unsigned u; } x, y, z, r;
    x.u = a; y.u = b; z.u = c;
    f16x2 s = x.h + y.h + z.h;
    f16x2 zero = { (_Float16)0.0f, (_Float16)0.0f };
    r.h = __builtin_elementwise_max(s, zero);
    return r.u;
}
static __device__ __forceinline__ unsigned hpack(float a, float b){
    union { f16x2 h; unsigned u; } pk;
    pk.h = (f16x2){ (_Float16)a, (_Float16)b };
    return pk.u;
}

// K_SETUP: precompute the LDS images k_fused linearly copies, and zero the
// per-b completion counters (workspace is re-poisoned every iteration).
__global__ __launch_bounds__(256) void k_setup(
        const float* __restrict__ emb, const float* __restrict__ cw,
        const float* __restrict__ cb, const float* __restrict__ Wa,
        unsigned* __restrict__ tblG, unsigned* __restrict__ wahG,
        int* __restrict__ cnt)
{
    int gid = blockIdx.x*256 + threadIdx.x;
    if (gid < 128) cnt[gid] = 0;
    if (gid < 1248){
        int k = gid / 416;          // 416 = 26*16
        int rem = gid - k*416;
        int l = rem >> 4;
        int cp = rem & 15;
        int c0 = cp*2;
        float v0 = 0.f, v1 = 0.f;
        #pragma unroll
        for (int i = 0; i < 5; i++){
            float e = emb[l*5 + i];
            v0 += cw[(c0*5 + i)*3 + k] * e;
            v1 += cw[((c0+1)*5 + i)*3 + k] * e;
        }
        if (k == 2){ v0 += cb[c0]; v1 += cb[c0+1]; }
        tblG[k*520 + l*20 + (cp & 3)*4 + (cp >> 2)] = hpack(v0, v1);
    }
    for (int i = gid; i < 8192; i += 1280){
        float2 t = ((const float2*)Wa)[i];
        unsigned byteoff = ((unsigned)i << 2) ^ ((((unsigned)i >> 6) & 7u) << 4);
        *(unsigned*)((char*)wahG + byteoff) = hpack(t.x, t.y);
    }
}

// K_FUSED v8 = v5 (R4, k_fused <=40.3us: setup-kernel + pure-copy prologue,
// grid (16,128)x256, bounds(256,2), two-half dt ILP) + R6's validated no-max
// softmax (w=exp(e) directly; |e|<~45 so f32-safe; chunks share a common
// scale) + FUSED FINISH: split-k completion via device-scope atomic counter.
// R6 post-mortem: folding setup per-block added ~4us VALU work x2048 blocks
// and perturbed regalloc to 68 VGPR (AGPR shuffling) -> 62us. Reverted.
// Finish: each block writes its 4 chunks + S, barrier (drains vmcnt), tid0
// threadfence (L2 writeback) + atomicAdd(cnt[b]); the 16th block for b
// fences (invalidate) and reduces 64 chunks -> out[b]. 127/128 finishes
// overlap other blocks' main loops; only the last b's finish (~2us) is tail.
__global__ __launch_bounds__(256, 2) void k_fused(
        const int* __restrict__ seq, const unsigned* __restrict__ tblG,
        const unsigned* __restrict__ wahG, const float* __restrict__ va,
        float* __restrict__ part, float* __restrict__ stats,
        int* __restrict__ cnt, float* __restrict__ out)
{
    __shared__ __align__(16) unsigned wahL[8192];      // 32 KB swizzled f16 Wa
    __shared__ __align__(16) unsigned tblH[1560];      // 6240 B perm tap table
    __shared__ unsigned short seqw16[4][132];          // pre-scaled offsets (x80)
    __shared__ __align__(16) float vaL[128];
    __shared__ int lastFlag;

    int tid = threadIdx.x;
    int b   = blockIdx.y;
    int x   = blockIdx.x;
    int n0  = x * 128;

    // ---- prologue: pure copies (one barrier) ----
    #pragma unroll
    for (int j = 0; j < 8; j++)
        ((uint4*)wahL)[tid + j*256] = ((const uint4*)wahG)[tid + j*256];
    for (int i = tid; i < 390; i += 256)
        ((uint4*)tblH)[i] = ((const uint4*)tblG)[i];
    if (tid < 128) vaL[tid] = va[tid];
    const int* sb = seq + (size_t)b * LSEQ;
    for (int i = tid; i < 4*132; i += 256){
        int s = i / 132, off = i - s*132;
        if (off < 130)
            seqw16[s][off] = (unsigned short)(sb[s*2048 + n0 + off] * 80);
    }
    __syncthreads();

    int w = tid >> 6, lane = tid & 63;
    int m = lane & 15, q = lane >> 4;
    const char* tb0 = (const char*)tblH + q*16;
    const char* tb1 = tb0 + 2080;
    const char* tb2 = tb1 + 2080;

    float accp[32];              // pooled partials, k = ki*32+q*8+t
    #pragma unroll
    for (int j = 0; j < 32; j++) accp[j] = 0.f;
    float Sw = 0.f;              // per-lane sum of exp(e) over own positions

    #pragma unroll
    for (int it = 0; it < 2; it++){
        int base = w*32 + it*16 + m;
        uint4 vfr[4];            // B-frags: lane's own position, 4 K-tiles
        {
            unsigned V[4][4];    // V[s][ki] = f16x2(chA,chB); cp=ki*4+q
            #pragma unroll
            for (int s = 0; s < 4; s++){
                unsigned oa = seqw16[s][base];
                unsigned ob = seqw16[s][base+1];
                unsigned oc = seqw16[s][base+2];
                uint4 t0 = *(const uint4*)(tb0 + oa);
                uint4 t1 = *(const uint4*)(tb1 + ob);
                uint4 t2 = *(const uint4*)(tb2 + oc);
                V[s][0] = h3relu(t0.x, t1.x, t2.x);
                V[s][1] = h3relu(t0.y, t1.y, t2.y);
                V[s][2] = h3relu(t0.z, t1.z, t2.z);
                V[s][3] = h3relu(t0.w, t1.w, t2.w);
            }
            #pragma unroll
            for (int ki = 0; ki < 4; ki++){
                uint4 o;
                o.x = __builtin_amdgcn_perm(V[1][ki], V[0][ki], 0x05040100u);  // A_s0,A_s1
                o.y = __builtin_amdgcn_perm(V[3][ki], V[2][ki], 0x05040100u);  // A_s2,A_s3
                o.z = __builtin_amdgcn_perm(V[1][ki], V[0][ki], 0x07060302u);  // B_s0,B_s1
                o.w = __builtin_amdgcn_perm(V[3][ki], V[2][ki], 0x07060302u);  // B_s2,B_s3
                vfr[ki] = o;
            }
        }

        // d_out in two halves of 4 dt-tiles: per ki, 4 batched A-reads then
        // 4 MFMAs into distinct accs (dep dist 4); acc dies into tanh/ep
        // before the next half. ep order: dt ascending, elem ascending.
        float ep = 0.f;
        #pragma unroll
        for (int h = 0; h < 2; h++){
            f32x4 acc[4];
            #pragma unroll
            for (int dd = 0; dd < 4; dd++) acc[dd] = (f32x4){0.f, 0.f, 0.f, 0.f};
            #pragma unroll
            for (int ki = 0; ki < 4; ki++){
                uint4 af[4];
                #pragma unroll
                for (int dd = 0; dd < 4; dd++){
                    int dt = h*4 + dd;
                    unsigned abyte = (unsigned)((dt*16 + m)*256 + ki*64 + q*16)
                                   ^ (((unsigned)(m & 7)) << 4);
                    af[dd] = *(const uint4*)((const char*)wahL + abyte);
                }
                union { uint4 u; f16x8 f; } bf; bf.u = vfr[ki];
                #pragma unroll
                for (int dd = 0; dd < 4; dd++){
                    union { uint4 u; f16x8 f; } a; a.u = af[dd];
                    acc[dd] = __builtin_amdgcn_mfma_f32_16x16x32_f16(a.f, bf.f, acc[dd], 0, 0, 0);
                }
            }
            #pragma unroll
            for (int dd = 0; dd < 4; dd++){
                int dt = h*4 + dd;
                const f32x4 vg = *(const f32x4*)&vaL[dt*16 + q*4];
                ep += vg[0] * tanh_fast(acc[dd][0]);
                ep += vg[1] * tanh_fast(acc[dd][1]);
                ep += vg[2] * tanh_fast(acc[dd][2]);
                ep += vg[3] * tanh_fast(acc[dd][3]);
            }
        }
        ep += __shfl_xor(ep, 16);
        ep += __shfl_xor(ep, 32);        // e[col m], replicated across q

        // NO-MAX softmax: w = exp(e) directly (|e| << 88, f32-safe).
        float wrl = __expf(ep);          // weight of THIS lane's own position
        Sw += wrl;                       // S-reduction deferred to wave end

        // pool from the lane's OWN V registers (no LDS, no shfl, no rescale)
        #pragma unroll
        for (int ki = 0; ki < 4; ki++){
            union { uint4 u; f16x2 h[4]; } vv; vv.u = vfr[ki];
            accp[ki*8 + 0] += wrl * (float)vv.h[0][0];
            accp[ki*8 + 1] += wrl * (float)vv.h[0][1];
            accp[ki*8 + 2] += wrl * (float)vv.h[1][0];
            accp[ki*8 + 3] += wrl * (float)vv.h[1][1];
            accp[ki*8 + 4] += wrl * (float)vv.h[2][0];
            accp[ki*8 + 5] += wrl * (float)vv.h[2][1];
            accp[ki*8 + 6] += wrl * (float)vv.h[3][0];
            accp[ki*8 + 7] += wrl * (float)vv.h[3][1];
        }
    }

    // reduce accp + Sw over the 16 position-lanes (m)
    #pragma unroll
    for (int j = 0; j < 32; j++){
        accp[j] += __shfl_xor(accp[j], 1);
        accp[j] += __shfl_xor(accp[j], 2);
        accp[j] += __shfl_xor(accp[j], 4);
        accp[j] += __shfl_xor(accp[j], 8);
    }
    Sw += __shfl_xor(Sw, 1);
    Sw += __shfl_xor(Sw, 2);
    Sw += __shfl_xor(Sw, 4);
    Sw += __shfl_xor(Sw, 8);            // S of this wave's 32 positions (q-repl)

    size_t chunk = ((size_t)b*16 + x)*4 + w;      // 64 chunks per b, c = pos/32
    if (m == 0){
        float* pd = part + chunk*128;
        #pragma unroll
        for (int ki = 0; ki < 4; ki++){
            float4 lo = { accp[ki*8+0], accp[ki*8+1], accp[ki*8+2], accp[ki*8+3] };
            float4 hi = { accp[ki*8+4], accp[ki*8+5], accp[ki*8+6], accp[ki*8+7] };
            *(float4*)(pd + ki*32 + q*8)     = lo;   // 16B-aligned (elem%4==0)
            *(float4*)(pd + ki*32 + q*8 + 4) = hi;
        }
    }
    if (lane == 0)
        stats[chunk] = Sw;

    // ---- fused finish (split-k completion) ----
    __syncthreads();                    // all chunk stores drained (vmcnt 0)
    if (tid == 0){
        __threadfence();                // release: write back to coherence point
        int old = atomicAdd(&cnt[b], 1);
        lastFlag = (old == 15);
    }
    __syncthreads();
    if (lastFlag){
        if (tid == 0) __threadfence();  // acquire: invalidate stale caches
        __syncthreads();
        if (tid < 128){
            const float* st = stats + (size_t)b*64;
            float S = 0.f;
            #pragma unroll 8
            for (int c = 0; c < 64; c++) S += st[c];
            const float* p = part + (size_t)b*64*128 + tid;
            float s = 0.f;
            #pragma unroll 8
            for (int c = 0; c < 64; c++) s += p[c*128];
            out[b*128 + tid] = s / S;
        }
    }
}

extern "C" void kernel_launch(void* const* d_in, const int* in_sizes, int n_in,
                              void* d_out, int out_size, void* d_ws, size_t ws_size,
                              hipStream_t stream)
{
    const int*   seq = (const int*)d_in[0];
    const float* emb = (const float*)d_in[1];
    const float* cw  = (const float*)d_in[2];
    const float* cb  = (const float*)d_in[3];
    const float* Wa  = (const float*)d_in[4];
    const float* va  = (const float*)d_in[5];
    float* out = (float*)d_out;

    char* wsb = (char*)d_ws;
    float*    part  = (float*)wsb;                         // 4 MiB (128*64*128 f32)
    float*    stats = (float*)(wsb + (8<<20));             // 32 KiB (128*64 f32)
    unsigned* tblG  = (unsigned*)(wsb + (12<<20));         // 6240 B
    unsigned* wahG  = (unsigned*)(wsb + (12<<20) + 32768); // 32 KiB (swizzled image)
    int*      cnt   = (int*)     (wsb + (12<<20) + 98304); // 512 B (128 counters)

    k_setup<<<5,            256, 0, stream>>>(emb, cw, cb, Wa, tblG, wahG, cnt);
    k_fused<<<dim3(16,128), 256, 0, stream>>>(seq, tblG, wahG, va, part, stats, cnt, out);
}

// Round 8
// 94.711 us; speedup vs baseline: 1.7396x; 1.7396x over previous
//
#include <hip/hip_runtime.h>

#define LSEQ 8194

typedef _Float16 f16x8 __attribute__((ext_vector_type(8)));
typedef _Float16 f16x2 __attribute__((ext_vector_type(2)));
typedef __attribute__((ext_vector_type(4))) float f32x4;

static __device__ __forceinline__ float tanh_fast(float x){
    float p = __expf(2.0f * x);
    float r = __builtin_amdgcn_rcpf(1.0f + p);
    return 1.0f - 2.0f * r;
}
// sum 3 packed-f16x2 taps + relu (v_pk_add_f16 + v_pk_max_f16)
static __device__ __forceinline__ unsigned h3relu(unsigned a, unsigned b, unsigned c){
    union { f16x2 h; unsigned u; } x, y, z, r;
    x.u = a; y.u = b; z.u = c;
    f16x2 s = x.h + y.h + z.h;
    f16x2 zero = { (_Float16)0.0f, (_Float16)0.0f };
    r.h = __builtin_elementwise_max(s, zero);
    return r.u;
}
static __device__ __forceinline__ unsigned hpack(float a, float b){
    union { f16x2 h; unsigned u; } pk;
    pk.h = (f16x2){ (_Float16)a, (_Float16)b };
    return pk.u;
}
// x + row_ror(x): VALU DPP cross-lane add within a 16-lane row (NO LDS pipe).
// ctrl: 0x121=ror1 0x122=ror2 0x124=ror4 0x128=ror8. Must be a macro: the
// builtin requires integer-constant args.
#define ROR_ADD(x, ctrl) ({ \
    union { float f; int i; } _s, _r; _s.f = (x); \
    _r.i = __builtin_amdgcn_update_dpp(0, _s.i, (ctrl), 0xF, 0xF, true); \
    (x) + _r.f; })

// K_SETUP: precompute the LDS images k_fused linearly copies.
__global__ __launch_bounds__(256) void k_setup(
        const float* __restrict__ emb, const float* __restrict__ cw,
        const float* __restrict__ cb, const float* __restrict__ Wa,
        unsigned* __restrict__ tblG, unsigned* __restrict__ wahG)
{
    int gid = blockIdx.x*256 + threadIdx.x;
    if (gid < 1248){
        int k = gid / 416;          // 416 = 26*16
        int rem = gid - k*416;
        int l = rem >> 4;
        int cp = rem & 15;
        int c0 = cp*2;
        float v0 = 0.f, v1 = 0.f;
        #pragma unroll
        for (int i = 0; i < 5; i++){
            float e = emb[l*5 + i];
            v0 += cw[(c0*5 + i)*3 + k] * e;
            v1 += cw[((c0+1)*5 + i)*3 + k] * e;
        }
        if (k == 2){ v0 += cb[c0]; v1 += cb[c0+1]; }
        tblG[k*520 + l*20 + (cp & 3)*4 + (cp >> 2)] = hpack(v0, v1);
    }
    for (int i = gid; i < 8192; i += 1280){
        float2 t = ((const float2*)Wa)[i];
        unsigned byteoff = ((unsigned)i << 2) ^ ((((unsigned)i >> 6) & 7u) << 4);
        *(unsigned*)((char*)wahG + byteoff) = hpack(t.x, t.y);
    }
}

// K_FUSED v9 — LDS-PIPE DIET on the v5 base (R4, best main loop ~39us).
// Pipe accounting (per CU, the invariant ~40us explained): gather reads
// ~15Kcy + A-frag reads ~30Kcy + final shfl-butterflies ~24Kcy (4.2K
// ds_bpermute!) + writes ~ 30us serialized LDS pipe; VALU 14us hides under.
// Cuts: (1) PAIRED TILES — one pass over both 16-pos tiles, each A-frag
// ds_read feeds 2 MFMAs (A-reads/wave 64->32); (2) DPP ROTATE-REDUCE —
// accp/Sw reduction over m-lanes (= a DPP row) via v_add+row_ror 1/2/4/8:
// VALU, zero LDS-pipe (removes all 4.2K ds-ops/CU); (3) single-pass: accp
// built AFTER the MFMA phase (not live during it; peak live ~100 < cap 128).
// No-max softmax kept (R6/R7-validated: |e|<~45, f32-safe; chunks share a
// common scale; kb2 = pure sum/divide). NO fused finish (R7: device-fence
// per block = disaster). Same chunk map as v8: 64 chunks/b, c = pos/32.
__global__ __launch_bounds__(256, 2) void k_fused(
        const int* __restrict__ seq, const unsigned* __restrict__ tblG,
        const unsigned* __restrict__ wahG, const float* __restrict__ va,
        float* __restrict__ part, float* __restrict__ stats)
{
    __shared__ __align__(16) unsigned wahL[8192];      // 32 KB swizzled f16 Wa
    __shared__ __align__(16) unsigned tblH[1560];      // 6240 B perm tap table
    __shared__ unsigned short seqw16[4][132];          // pre-scaled offsets (x80)
    __shared__ __align__(16) float vaL[128];

    int tid = threadIdx.x;
    int b   = blockIdx.y;
    int x   = blockIdx.x;
    int n0  = x * 128;

    // ---- prologue: pure copies (one barrier) ----
    #pragma unroll
    for (int j = 0; j < 8; j++)
        ((uint4*)wahL)[tid + j*256] = ((const uint4*)wahG)[tid + j*256];
    for (int i = tid; i < 390; i += 256)
        ((uint4*)tblH)[i] = ((const uint4*)tblG)[i];
    if (tid < 128) vaL[tid] = va[tid];
    const int* sb = seq + (size_t)b * LSEQ;
    for (int i = tid; i < 4*132; i += 256){
        int s = i / 132, off = i - s*132;
        if (off < 130)
            seqw16[s][off] = (unsigned short)(sb[s*2048 + n0 + off] * 80);
    }
    __syncthreads();   // the ONLY barrier

    int w = tid >> 6, lane = tid & 63;
    int m = lane & 15, q = lane >> 4;
    const char* tb0 = (const char*)tblH + q*16;
    const char* tb1 = tb0 + 2080;
    const char* tb2 = tb1 + 2080;

    // ---- gen BOTH tiles' B-frags (V scratch dies per scope) ----
    uint4 vfr0[4], vfr1[4];
    {
        int base = w*32 + m;
        unsigned V[4][4];
        #pragma unroll
        for (int s = 0; s < 4; s++){
            unsigned oa = seqw16[s][base];
            unsigned ob = seqw16[s][base+1];
            unsigned oc = seqw16[s][base+2];
            uint4 t0 = *(const uint4*)(tb0 + oa);
            uint4 t1 = *(const uint4*)(tb1 + ob);
            uint4 t2 = *(const uint4*)(tb2 + oc);
            V[s][0] = h3relu(t0.x, t1.x, t2.x);
            V[s][1] = h3relu(t0.y, t1.y, t2.y);
            V[s][2] = h3relu(t0.z, t1.z, t2.z);
            V[s][3] = h3relu(t0.w, t1.w, t2.w);
        }
        #pragma unroll
        for (int ki = 0; ki < 4; ki++){
            uint4 o;
            o.x = __builtin_amdgcn_perm(V[1][ki], V[0][ki], 0x05040100u);
            o.y = __builtin_amdgcn_perm(V[3][ki], V[2][ki], 0x05040100u);
            o.z = __builtin_amdgcn_perm(V[1][ki], V[0][ki], 0x07060302u);
            o.w = __builtin_amdgcn_perm(V[3][ki], V[2][ki], 0x07060302u);
            vfr0[ki] = o;
        }
    }
    {
        int base = w*32 + 16 + m;
        unsigned V[4][4];
        #pragma unroll
        for (int s = 0; s < 4; s++){
            unsigned oa = seqw16[s][base];
            unsigned ob = seqw16[s][base+1];
            unsigned oc = seqw16[s][base+2];
            uint4 t0 = *(const uint4*)(tb0 + oa);
            uint4 t1 = *(const uint4*)(tb1 + ob);
            uint4 t2 = *(const uint4*)(tb2 + oc);
            V[s][0] = h3relu(t0.x, t1.x, t2.x);
            V[s][1] = h3relu(t0.y, t1.y, t2.y);
            V[s][2] = h3relu(t0.z, t1.z, t2.z);
            V[s][3] = h3relu(t0.w, t1.w, t2.w);
        }
        #pragma unroll
        for (int ki = 0; ki < 4; ki++){
            uint4 o;
            o.x = __builtin_amdgcn_perm(V[1][ki], V[0][ki], 0x05040100u);
            o.y = __builtin_amdgcn_perm(V[3][ki], V[2][ki], 0x05040100u);
            o.z = __builtin_amdgcn_perm(V[1][ki], V[0][ki], 0x07060302u);
            o.w = __builtin_amdgcn_perm(V[3][ki], V[2][ki], 0x07060302u);
            vfr1[ki] = o;
        }
    }

    // ---- MFMA: two halves of 4 dt-tiles; each A-read feeds BOTH tiles ----
    float ep0 = 0.f, ep1 = 0.f;
    #pragma unroll
    for (int h = 0; h < 2; h++){
        f32x4 acc0[4], acc1[4];
        #pragma unroll
        for (int dd = 0; dd < 4; dd++){
            acc0[dd] = (f32x4){0.f, 0.f, 0.f, 0.f};
            acc1[dd] = (f32x4){0.f, 0.f, 0.f, 0.f};
        }
        #pragma unroll
        for (int ki = 0; ki < 4; ki++){
            uint4 af[4];
            #pragma unroll
            for (int dd = 0; dd < 4; dd++){
                int dt = h*4 + dd;
                unsigned abyte = (unsigned)((dt*16 + m)*256 + ki*64 + q*16)
                               ^ (((unsigned)(m & 7)) << 4);
                af[dd] = *(const uint4*)((const char*)wahL + abyte);
            }
            union { uint4 u; f16x8 f; } b0, b1;
            b0.u = vfr0[ki]; b1.u = vfr1[ki];
            #pragma unroll
            for (int dd = 0; dd < 4; dd++){
                union { uint4 u; f16x8 f; } a; a.u = af[dd];
                acc0[dd] = __builtin_amdgcn_mfma_f32_16x16x32_f16(a.f, b0.f, acc0[dd], 0, 0, 0);
                acc1[dd] = __builtin_amdgcn_mfma_f32_16x16x32_f16(a.f, b1.f, acc1[dd], 0, 0, 0);
            }
        }
        #pragma unroll
        for (int dd = 0; dd < 4; dd++){
            int dt = h*4 + dd;
            const f32x4 vg = *(const f32x4*)&vaL[dt*16 + q*4];
            ep0 += vg[0] * tanh_fast(acc0[dd][0]);
            ep0 += vg[1] * tanh_fast(acc0[dd][1]);
            ep0 += vg[2] * tanh_fast(acc0[dd][2]);
            ep0 += vg[3] * tanh_fast(acc0[dd][3]);
            ep1 += vg[0] * tanh_fast(acc1[dd][0]);
            ep1 += vg[1] * tanh_fast(acc1[dd][1]);
            ep1 += vg[2] * tanh_fast(acc1[dd][2]);
            ep1 += vg[3] * tanh_fast(acc1[dd][3]);
        }
    }
    ep0 += __shfl_xor(ep0, 16);
    ep0 += __shfl_xor(ep0, 32);          // e[tile0 col m], replicated over q
    ep1 += __shfl_xor(ep1, 16);
    ep1 += __shfl_xor(ep1, 32);

    // NO-MAX softmax weights (|e| << 88, f32-safe)
    float w0 = __expf(ep0);
    float w1 = __expf(ep1);
    float Sw = w0 + w1;

    // ---- pool from the lane's OWN V registers (built AFTER MFMA phase) ----
    float accp[32];                      // k = ki*32 + q*8 + t
    #pragma unroll
    for (int ki = 0; ki < 4; ki++){
        union { uint4 u; f16x2 h[4]; } v0, v1;
        v0.u = vfr0[ki]; v1.u = vfr1[ki];
        #pragma unroll
        for (int t = 0; t < 4; t++){
            accp[ki*8 + ((t>>1)<<2) + (t&1)*1 + 0] = 0.f; // placeholder (overwritten below)
        }
        accp[ki*8 + 0] = w0 * (float)v0.h[0][0] + w1 * (float)v1.h[0][0];
        accp[ki*8 + 1] = w0 * (float)v0.h[0][1] + w1 * (float)v1.h[0][1];
        accp[ki*8 + 2] = w0 * (float)v0.h[1][0] + w1 * (float)v1.h[1][0];
        accp[ki*8 + 3] = w0 * (float)v0.h[1][1] + w1 * (float)v1.h[1][1];
        accp[ki*8 + 4] = w0 * (float)v0.h[2][0] + w1 * (float)v1.h[2][0];
        accp[ki*8 + 5] = w0 * (float)v0.h[2][1] + w1 * (float)v1.h[2][1];
        accp[ki*8 + 6] = w0 * (float)v0.h[3][0] + w1 * (float)v1.h[3][0];
        accp[ki*8 + 7] = w0 * (float)v0.h[3][1] + w1 * (float)v1.h[3][1];
    }

    // ---- reduce over the 16 m-lanes via DPP row_ror (VALU, no LDS pipe) ----
    #pragma unroll
    for (int j = 0; j < 32; j++){
        accp[j] = ROR_ADD(accp[j], 0x121);   // ror1
        accp[j] = ROR_ADD(accp[j], 0x122);   // ror2
        accp[j] = ROR_ADD(accp[j], 0x124);   // ror4
        accp[j] = ROR_ADD(accp[j], 0x128);   // ror8
    }
    Sw = ROR_ADD(Sw, 0x121);
    Sw = ROR_ADD(Sw, 0x122);
    Sw = ROR_ADD(Sw, 0x124);
    Sw = ROR_ADD(Sw, 0x128);

    size_t chunk = ((size_t)b*16 + x)*4 + w;      // 64 chunks per b, c = pos/32
    if (m == 0){
        float* pd = part + chunk*128;
        #pragma unroll
        for (int ki = 0; ki < 4; ki++){
            float4 lo = { accp[ki*8+0], accp[ki*8+1], accp[ki*8+2], accp[ki*8+3] };
            float4 hi = { accp[ki*8+4], accp[ki*8+5], accp[ki*8+6], accp[ki*8+7] };
            *(float4*)(pd + ki*32 + q*8)     = lo;   // 16B-aligned (elem%4==0)
            *(float4*)(pd + ki*32 + q*8 + 4) = hi;
        }
    }
    if (lane == 0)
        stats[chunk] = Sw;
}

// KB2: combine 64 chunk partials per b — common scale, pure sum/divide.
__global__ __launch_bounds__(128) void kb2_finish(const float* __restrict__ part,
        const float* __restrict__ stats, float* __restrict__ out)
{
    int b = blockIdx.x, d = threadIdx.x;
    const float* st = stats + (size_t)b*64;
    float S = 0.f;
    #pragma unroll 8
    for (int c = 0; c < 64; c++) S += st[c];
    const float* p = part + (size_t)b*64*128 + d;
    float s = 0.f;
    #pragma unroll 8
    for (int c = 0; c < 64; c++) s += p[c*128];
    out[b*128 + d] = s / S;
}

extern "C" void kernel_launch(void* const* d_in, const int* in_sizes, int n_in,
                              void* d_out, int out_size, void* d_ws, size_t ws_size,
                              hipStream_t stream)
{
    const int*   seq = (const int*)d_in[0];
    const float* emb = (const float*)d_in[1];
    const float* cw  = (const float*)d_in[2];
    const float* cb  = (const float*)d_in[3];
    const float* Wa  = (const float*)d_in[4];
    const float* va  = (const float*)d_in[5];
    float* out = (float*)d_out;

    char* wsb = (char*)d_ws;
    float*    part  = (float*)wsb;                         // 4 MiB (128*64*128 f32)
    float*    stats = (float*)(wsb + (8<<20));             // 32 KiB (128*64 f32)
    unsigned* tblG  = (unsigned*)(wsb + (12<<20));         // 6240 B
    unsigned* wahG  = (unsigned*)(wsb + (12<<20) + 32768); // 32 KiB (swizzled image)

    k_setup   <<<5,            256, 0, stream>>>(emb, cw, cb, Wa, tblG, wahG);
    k_fused   <<<dim3(16,128), 256, 0, stream>>>(seq, tblG, wahG, va, part, stats);
    kb2_finish<<<128,          128, 0, stream>>>(part, stats, out);
}

// Round 9
// 93.391 us; speedup vs baseline: 1.7641x; 1.0141x over previous
//
#include <hip/hip_runtime.h>

#define LSEQ 8194

typedef _Float16 f16x8 __attribute__((ext_vector_type(8)));
typedef _Float16 f16x2 __attribute__((ext_vector_type(2)));
typedef __attribute__((ext_vector_type(4))) float f32x4;

static __device__ __forceinline__ float tanh_fast(float x){
    float p = __expf(2.0f * x);
    float r = __builtin_amdgcn_rcpf(1.0f + p);
    return 1.0f - 2.0f * r;
}
// sum 3 packed-f16x2 taps + relu (v_pk_add_f16 + v_pk_max_f16)
static __device__ __forceinline__ unsigned h3relu(unsigned a, unsigned b, unsigned c){
    union { f16x2 h; unsigned u; } x, y, z, r;
    x.u = a; y.u = b; z.u = c;
    f16x2 s = x.h + y.h + z.h;
    f16x2 zero = { (_Float16)0.0f, (_Float16)0.0f };
    r.h = __builtin_elementwise_max(s, zero);
    return r.u;
}
static __device__ __forceinline__ unsigned hpack(float a, float b){
    union { f16x2 h; unsigned u; } pk;
    pk.h = (f16x2){ (_Float16)a, (_Float16)b };
    return pk.u;
}
// x + row_ror(x): VALU DPP cross-lane add within a 16-lane row (NO LDS pipe).
#define ROR_ADD(x, ctrl) ({ \
    union { float f; int i; } _s, _r; _s.f = (x); \
    _r.i = __builtin_amdgcn_update_dpp(0, _s.i, (ctrl), 0xF, 0xF, true); \
    (x) + _r.f; })

// K_SETUP: tap table (unchanged) + Wa f16 image in FRAGMENT ORDER:
// uint4 u = (dt*4+ki)*64 + lane  holds words  (dt*16+m)*64 + ki*16 + q*4 + j
// (m=lane&15, q=lane>>4, j=0..3; word i = hpack(Wa[2i],Wa[2i+1]) — same
// packs as always, only memory placement changes). A wave's A-frag read is
// then ONE lane-contiguous coalesced 1KB global_load_dwordx4, L1-resident.
__global__ __launch_bounds__(256) void k_setup(
        const float* __restrict__ emb, const float* __restrict__ cw,
        const float* __restrict__ cb, const float* __restrict__ Wa,
        unsigned* __restrict__ tblG, unsigned* __restrict__ wahG)
{
    int gid = blockIdx.x*256 + threadIdx.x;
    if (gid < 1248){
        int k = gid / 416;          // 416 = 26*16
        int rem = gid - k*416;
        int l = rem >> 4;
        int cp = rem & 15;
        int c0 = cp*2;
        float v0 = 0.f, v1 = 0.f;
        #pragma unroll
        for (int i = 0; i < 5; i++){
            float e = emb[l*5 + i];
            v0 += cw[(c0*5 + i)*3 + k] * e;
            v1 += cw[((c0+1)*5 + i)*3 + k] * e;
        }
        if (k == 2){ v0 += cb[c0]; v1 += cb[c0+1]; }
        tblG[k*520 + l*20 + (cp & 3)*4 + (cp >> 2)] = hpack(v0, v1);
    }
    for (int u = gid; u < 2048; u += 1280){
        int lane = u & 63, dtki = u >> 6;
        int dt = dtki >> 2, ki = dtki & 3;
        int m = lane & 15, q = lane >> 4;
        const float2* src = (const float2*)Wa + ((dt*16 + m)*64 + ki*16 + q*4);
        float2 s0 = src[0], s1 = src[1], s2 = src[2], s3 = src[3];
        uint4 o;
        o.x = hpack(s0.x, s0.y);
        o.y = hpack(s1.x, s1.y);
        o.z = hpack(s2.x, s2.y);
        o.w = hpack(s3.x, s3.y);
        ((uint4*)wahG)[u] = o;
    }
}

// K_FUSED v10 = v9 (R8: paired tiles, DPP reduce, no-max softmax, 94.7us)
// with Wa EVICTED FROM LDS: A-frags read from the fragment-ordered global
// image through L1 (32KB = exactly L1-resident; every block reuses it).
// Wins: (1) wave LDS ops ~45% down (A-reads + image-copy move to the idle
// VMEM pipe); (2) LDS 40960->~8KB so occupancy cap 2-3 -> 4+ blocks/CU;
// (3) no swizzle; (4) shorter prologue. A-loads batched 8-wide (2ki x 4dd,
// one vmcnt covers 8) -> ~116 VGPR+AGPR, under the 128 4-wave/SIMD line.
// ki-ascending accumulation per acc preserved -> bit-identical MFMA inputs.
__global__ __launch_bounds__(256, 2) void k_fused(
        const int* __restrict__ seq, const unsigned* __restrict__ tblG,
        const unsigned* __restrict__ wahG, const float* __restrict__ va,
        float* __restrict__ part, float* __restrict__ stats)
{
    __shared__ __align__(16) unsigned tblH[1560];      // 6240 B perm tap table
    __shared__ unsigned short seqw16[4][132];          // pre-scaled offsets (x80)
    __shared__ __align__(16) float vaL[128];

    int tid = threadIdx.x;
    int b   = blockIdx.y;
    int x   = blockIdx.x;
    int n0  = x * 128;

    // ---- prologue: small copies (one barrier) ----
    for (int i = tid; i < 390; i += 256)
        ((uint4*)tblH)[i] = ((const uint4*)tblG)[i];
    if (tid < 128) vaL[tid] = va[tid];
    const int* sb = seq + (size_t)b * LSEQ;
    for (int i = tid; i < 4*132; i += 256){
        int s = i / 132, off = i - s*132;
        if (off < 130)
            seqw16[s][off] = (unsigned short)(sb[s*2048 + n0 + off] * 80);
    }
    __syncthreads();   // the ONLY barrier

    int w = tid >> 6, lane = tid & 63;
    int m = lane & 15, q = lane >> 4;
    const char* tb0 = (const char*)tblH + q*16;
    const char* tb1 = tb0 + 2080;
    const char* tb2 = tb1 + 2080;
    const uint4* wa4 = (const uint4*)wahG + lane;      // lane-contiguous frags

    // ---- gen BOTH tiles' B-frags (V scratch dies per scope) ----
    uint4 vfr0[4], vfr1[4];
    {
        int base = w*32 + m;
        unsigned V[4][4];
        #pragma unroll
        for (int s = 0; s < 4; s++){
            unsigned oa = seqw16[s][base];
            unsigned ob = seqw16[s][base+1];
            unsigned oc = seqw16[s][base+2];
            uint4 t0 = *(const uint4*)(tb0 + oa);
            uint4 t1 = *(const uint4*)(tb1 + ob);
            uint4 t2 = *(const uint4*)(tb2 + oc);
            V[s][0] = h3relu(t0.x, t1.x, t2.x);
            V[s][1] = h3relu(t0.y, t1.y, t2.y);
            V[s][2] = h3relu(t0.z, t1.z, t2.z);
            V[s][3] = h3relu(t0.w, t1.w, t2.w);
        }
        #pragma unroll
        for (int ki = 0; ki < 4; ki++){
            uint4 o;
            o.x = __builtin_amdgcn_perm(V[1][ki], V[0][ki], 0x05040100u);
            o.y = __builtin_amdgcn_perm(V[3][ki], V[2][ki], 0x05040100u);
            o.z = __builtin_amdgcn_perm(V[1][ki], V[0][ki], 0x07060302u);
            o.w = __builtin_amdgcn_perm(V[3][ki], V[2][ki], 0x07060302u);
            vfr0[ki] = o;
        }
    }
    {
        int base = w*32 + 16 + m;
        unsigned V[4][4];
        #pragma unroll
        for (int s = 0; s < 4; s++){
            unsigned oa = seqw16[s][base];
            unsigned ob = seqw16[s][base+1];
            unsigned oc = seqw16[s][base+2];
            uint4 t0 = *(const uint4*)(tb0 + oa);
            uint4 t1 = *(const uint4*)(tb1 + ob);
            uint4 t2 = *(const uint4*)(tb2 + oc);
            V[s][0] = h3relu(t0.x, t1.x, t2.x);
            V[s][1] = h3relu(t0.y, t1.y, t2.y);
            V[s][2] = h3relu(t0.z, t1.z, t2.z);
            V[s][3] = h3relu(t0.w, t1.w, t2.w);
        }
        #pragma unroll
        for (int ki = 0; ki < 4; ki++){
            uint4 o;
            o.x = __builtin_amdgcn_perm(V[1][ki], V[0][ki], 0x05040100u);
            o.y = __builtin_amdgcn_perm(V[3][ki], V[2][ki], 0x05040100u);
            o.z = __builtin_amdgcn_perm(V[1][ki], V[0][ki], 0x07060302u);
            o.w = __builtin_amdgcn_perm(V[3][ki], V[2][ki], 0x07060302u);
            vfr1[ki] = o;
        }
    }

    // ---- MFMA: 2 halves x 2 ki-pairs; per batch 8 coalesced A-loads feed
    //      16 MFMAs (both tiles). acc accumulation order stays ki-ascending.
    float ep0 = 0.f, ep1 = 0.f;
    #pragma unroll
    for (int h = 0; h < 2; h++){
        f32x4 acc0[4], acc1[4];
        #pragma unroll
        for (int dd = 0; dd < 4; dd++){
            acc0[dd] = (f32x4){0.f, 0.f, 0.f, 0.f};
            acc1[dd] = (f32x4){0.f, 0.f, 0.f, 0.f};
        }
        #pragma unroll
        for (int kp = 0; kp < 2; kp++){
            uint4 af[8];                 // [kk*4+dd], kk = ki-kp*2
            #pragma unroll
            for (int kk = 0; kk < 2; kk++)
                #pragma unroll
                for (int dd = 0; dd < 4; dd++){
                    int dt = h*4 + dd, ki = kp*2 + kk;
                    af[kk*4+dd] = wa4[(dt*4 + ki) << 6];
                }
            #pragma unroll
            for (int kk = 0; kk < 2; kk++){
                int ki = kp*2 + kk;
                union { uint4 u; f16x8 f; } b0, b1;
                b0.u = vfr0[ki]; b1.u = vfr1[ki];
                #pragma unroll
                for (int dd = 0; dd < 4; dd++){
                    union { uint4 u; f16x8 f; } a; a.u = af[kk*4+dd];
                    acc0[dd] = __builtin_amdgcn_mfma_f32_16x16x32_f16(a.f, b0.f, acc0[dd], 0, 0, 0);
                    acc1[dd] = __builtin_amdgcn_mfma_f32_16x16x32_f16(a.f, b1.f, acc1[dd], 0, 0, 0);
                }
            }
        }
        #pragma unroll
        for (int dd = 0; dd < 4; dd++){
            int dt = h*4 + dd;
            const f32x4 vg = *(const f32x4*)&vaL[dt*16 + q*4];
            ep0 += vg[0] * tanh_fast(acc0[dd][0]);
            ep0 += vg[1] * tanh_fast(acc0[dd][1]);
            ep0 += vg[2] * tanh_fast(acc0[dd][2]);
            ep0 += vg[3] * tanh_fast(acc0[dd][3]);
            ep1 += vg[0] * tanh_fast(acc1[dd][0]);
            ep1 += vg[1] * tanh_fast(acc1[dd][1]);
            ep1 += vg[2] * tanh_fast(acc1[dd][2]);
            ep1 += vg[3] * tanh_fast(acc1[dd][3]);
        }
    }
    ep0 += __shfl_xor(ep0, 16);
    ep0 += __shfl_xor(ep0, 32);          // e[tile0 col m], replicated over q
    ep1 += __shfl_xor(ep1, 16);
    ep1 += __shfl_xor(ep1, 32);

    // NO-MAX softmax weights (|e| << 88, f32-safe)
    float w0 = __expf(ep0);
    float w1 = __expf(ep1);
    float Sw = w0 + w1;

    // ---- pool from the lane's OWN V registers (after MFMA phase) ----
    float accp[32];                      // k = ki*32 + q*8 + t
    #pragma unroll
    for (int ki = 0; ki < 4; ki++){
        union { uint4 u; f16x2 h[4]; } v0, v1;
        v0.u = vfr0[ki]; v1.u = vfr1[ki];
        accp[ki*8 + 0] = w0 * (float)v0.h[0][0] + w1 * (float)v1.h[0][0];
        accp[ki*8 + 1] = w0 * (float)v0.h[0][1] + w1 * (float)v1.h[0][1];
        accp[ki*8 + 2] = w0 * (float)v0.h[1][0] + w1 * (float)v1.h[1][0];
        accp[ki*8 + 3] = w0 * (float)v0.h[1][1] + w1 * (float)v1.h[1][1];
        accp[ki*8 + 4] = w0 * (float)v0.h[2][0] + w1 * (float)v1.h[2][0];
        accp[ki*8 + 5] = w0 * (float)v0.h[2][1] + w1 * (float)v1.h[2][1];
        accp[ki*8 + 6] = w0 * (float)v0.h[3][0] + w1 * (float)v1.h[3][0];
        accp[ki*8 + 7] = w0 * (float)v0.h[3][1] + w1 * (float)v1.h[3][1];
    }

    // ---- reduce over the 16 m-lanes via DPP row_ror (VALU, no LDS pipe) ----
    #pragma unroll
    for (int j = 0; j < 32; j++){
        accp[j] = ROR_ADD(accp[j], 0x121);   // ror1
        accp[j] = ROR_ADD(accp[j], 0x122);   // ror2
        accp[j] = ROR_ADD(accp[j], 0x124);   // ror4
        accp[j] = ROR_ADD(accp[j], 0x128);   // ror8
    }
    Sw = ROR_ADD(Sw, 0x121);
    Sw = ROR_ADD(Sw, 0x122);
    Sw = ROR_ADD(Sw, 0x124);
    Sw = ROR_ADD(Sw, 0x128);

    size_t chunk = ((size_t)b*16 + x)*4 + w;      // 64 chunks per b, c = pos/32
    if (m == 0){
        float* pd = part + chunk*128;
        #pragma unroll
        for (int ki = 0; ki < 4; ki++){
            float4 lo = { accp[ki*8+0], accp[ki*8+1], accp[ki*8+2], accp[ki*8+3] };
            float4 hi = { accp[ki*8+4], accp[ki*8+5], accp[ki*8+6], accp[ki*8+7] };
            *(float4*)(pd + ki*32 + q*8)     = lo;   // 16B-aligned (elem%4==0)
            *(float4*)(pd + ki*32 + q*8 + 4) = hi;
        }
    }
    if (lane == 0)
        stats[chunk] = Sw;
}

// KB2: combine 64 chunk partials per b — common scale, pure sum/divide.
__global__ __launch_bounds__(128) void kb2_finish(const float* __restrict__ part,
        const float* __restrict__ stats, float* __restrict__ out)
{
    int b = blockIdx.x, d = threadIdx.x;
    const float* st = stats + (size_t)b*64;
    float S = 0.f;
    #pragma unroll 8
    for (int c = 0; c < 64; c++) S += st[c];
    const float* p = part + (size_t)b*64*128 + d;
    float s = 0.f;
    #pragma unroll 8
    for (int c = 0; c < 64; c++) s += p[c*128];
    out[b*128 + d] = s / S;
}

extern "C" void kernel_launch(void* const* d_in, const int* in_sizes, int n_in,
                              void* d_out, int out_size, void* d_ws, size_t ws_size,
                              hipStream_t stream)
{
    const int*   seq = (const int*)d_in[0];
    const float* emb = (const float*)d_in[1];
    const float* cw  = (const float*)d_in[2];
    const float* cb  = (const float*)d_in[3];
    const float* Wa  = (const float*)d_in[4];
    const float* va  = (const float*)d_in[5];
    float* out = (float*)d_out;

    char* wsb = (char*)d_ws;
    float*    part  = (float*)wsb;                         // 4 MiB (128*64*128 f32)
    float*    stats = (float*)(wsb + (8<<20));             // 32 KiB (128*64 f32)
    unsigned* tblG  = (unsigned*)(wsb + (12<<20));         // 6240 B
    unsigned* wahG  = (unsigned*)(wsb + (12<<20) + 32768); // 32 KiB (frag-ordered)

    k_setup   <<<5,            256, 0, stream>>>(emb, cw, cb, Wa, tblG, wahG);
    k_fused   <<<dim3(16,128), 256, 0, stream>>>(seq, tblG, wahG, va, part, stats);
    kb2_finish<<<128,          128, 0, stream>>>(part, stats, out);
}